// Round 7
// baseline (1678.833 us; speedup 1.0000x reference)
//
#include <hip/hip_runtime.h>

#define NPTS 1000000
#define KNBR 27
#define NCH 64
#define EPSV 1e-5f

typedef __attribute__((ext_vector_type(8))) short bf16x8;   // 8 bf16 = 4 VGPRs
typedef __attribute__((ext_vector_type(4))) float f32x4;    // MFMA C/D frag / vec4 f32
typedef __attribute__((ext_vector_type(8))) unsigned short ushort8;

__device__ inline unsigned short f2bf(float f) {            // RNE fp32->bf16
    unsigned int x = __float_as_uint(f);
    unsigned int r = x + 0x7FFFu + ((x >> 16) & 1u);
    return (unsigned short)(r >> 16);
}
__device__ inline float bf2f(unsigned short u) {
    return __uint_as_float(((unsigned int)u) << 16);
}

// ---------------------------------------------------------------------------
// Mask dtype autodetect (verified working R2-R6).
// ---------------------------------------------------------------------------
__global__ void detect_mask_kernel(const unsigned int* __restrict__ mask32,
                                   int* __restrict__ flag)
{
    __shared__ int cnt;
    if (threadIdx.x == 0) cnt = 0;
    __syncthreads();
    int c = 0;
    for (int i = threadIdx.x; i < 4096; i += 256)
        if (mask32[i] <= 1u) c++;
    atomicAdd(&cnt, c);
    __syncthreads();
    if (threadIdx.x == 0) *flag = (cnt >= 3900) ? 1 : 0;
}

// feats fp32 -> bf16
__global__ __launch_bounds__(256)
void cvt_feats_kernel(const float* __restrict__ in, unsigned short* __restrict__ outp)
{
    const long nchunk = (long)NPTS * 32 / 8;   // 4M
    const long stride = (long)gridDim.x * 256;
    const float4* f4 = (const float4*)in;
    ushort8* o8 = (ushort8*)outp;
    for (long i = (long)blockIdx.x * 256 + threadIdx.x; i < nchunk; i += stride) {
        float4 a = f4[2 * i], b = f4[2 * i + 1];
        ushort8 o;
        o[0] = f2bf(a.x); o[1] = f2bf(a.y); o[2] = f2bf(a.z); o[3] = f2bf(a.w);
        o[4] = f2bf(b.x); o[5] = f2bf(b.y); o[6] = f2bf(b.z); o[7] = f2bf(b.w);
        o8[i] = o;
    }
}

// zero the sentinel gather rows (row N of fb and h1) — masked gathers land here
__global__ void zero_rows_kernel(unsigned short* __restrict__ fb,
                                 unsigned short* __restrict__ h1)
{
    const int t = threadIdx.x;
    if (t < 32) fb[(size_t)NPTS * 32 + t] = 0;
    if (t < 64) h1[(size_t)NPTS * 64 + t] = 0;
}

// ---------------------------------------------------------------------------
// W[k][ci][co] fp32 -> MFMA-fragment-ordered bf16:
//   wtf[k][ks][c][lane][j]  with  ci = ks*32 + (lane>>4)*8 + j,  co = c*16 + (lane&15)
// ---------------------------------------------------------------------------
template<int CIN>
__global__ __launch_bounds__(256)
void transpose_w_frag_kernel(const float* __restrict__ W, unsigned short* __restrict__ wtf)
{
    const int k = blockIdx.x;
    constexpr int TOT = CIN * 64;
    for (int e = threadIdx.x; e < TOT; e += 256) {
        const int j = e & 7, l = (e >> 3) & 63, c = (e >> 9) & 3, ks = e >> 11;
        const int ci = ks * 32 + (l >> 4) * 8 + j;
        const int co = c * 16 + (l & 15);
        wtf[(size_t)k * TOT + e] = f2bf(W[((size_t)k * CIN + ci) * 64 + co]);
    }
}

// ---------------------------------------------------------------------------
// MFMA conv, software-pipelined. Block = 4 waves x 128 points; wave = 32 pts.
// Gathers are UNCONDITIONAL (masked -> zero row NPTS) so they pipeline.
// A prefetched 2 k-iters ahead (3 static buffers, full unroll), midx indices
// prefetched 3 ahead into registers. B loaded per-iter (L2-hot).
// BN stats fused into epilogue; final f32 output stored nontemporal.
// ---------------------------------------------------------------------------
template<int CIN, bool OUT_BF16>
__global__ __launch_bounds__(256, 3)
void conv_mfma_kernel(const unsigned short* __restrict__ src,  // [N+1][CIN] bf16
                      const unsigned short* __restrict__ wtf,  // frag-ordered W
                      const int* __restrict__ nbr,
                      const unsigned char* __restrict__ mask8,
                      const int* __restrict__ mask32,
                      const int* __restrict__ mflag,
                      void* __restrict__ outp,
                      float* __restrict__ sums)   // [64] sum | [64] sumsq
{
    constexpr int KS = CIN / 32;
    __shared__ int midx[128 * KNBR];        // 13.5 KB
    __shared__ float sred[64], qred[64];

    const int t = threadIdx.x;
    const int pbase = blockIdx.x * 128;

    if (t < 64) { sred[t] = 0.f; qred[t] = 0.f; }

    // ---- stage merged nbr+mask (masked/OOB -> zero row NPTS); nt streams ----
    const bool m32 = (*mflag != 0);
    for (int i = t; i < 128 * KNBR; i += 256) {
        const int p = i / KNBR;
        int v = NPTS;
        if (pbase + p < NPTS) {
            const int gi = pbase * KNBR + i;
            const int idxv = __builtin_nontemporal_load(&nbr[gi]);
            const bool mv = m32 ? (__builtin_nontemporal_load(&mask32[gi]) != 0)
                                : (__builtin_nontemporal_load(&mask8[gi]) != 0);
            v = mv ? idxv : NPTS;
        }
        midx[i] = v;
    }
    __syncthreads();

    const int wave = t >> 6;
    const int lane = t & 63;
    const int lr = lane & 15;    // A row within 16-row frag / output col
    const int kg = lane >> 4;    // k-subgroup
    const int wpt = wave * 32;
    const int mb0 = (wpt + lr) * KNBR;        // ai = 0
    const int mb1 = (wpt + 16 + lr) * KNBR;   // ai = 1

    f32x4 acc[4][2];
#pragma unroll
    for (int c = 0; c < 4; ++c)
#pragma unroll
        for (int a = 0; a < 2; ++a) acc[c][a] = (f32x4){0.f, 0.f, 0.f, 0.f};

    const int koff = kg * 8;     // element offset within ks-slice

    // A buffers: [slot][ks][ai]; all indices compile-time via full unroll
    bf16x8 A[3][KS][2];
    int mi0c, mi1c;              // rotating midx prefetch (k+2 then k+3...)

    // ---- prologue: A(k=0)->slot0, A(k=1)->slot1, midx(k=2) ----
    {
        const int a00 = midx[mb0 + 0], a01 = midx[mb1 + 0];
        const int a10 = midx[mb0 + 1], a11 = midx[mb1 + 1];
#pragma unroll
        for (int ks = 0; ks < KS; ++ks) {
            A[0][ks][0] = *(const bf16x8*)(src + (size_t)a00 * CIN + ks * 32 + koff);
            A[0][ks][1] = *(const bf16x8*)(src + (size_t)a01 * CIN + ks * 32 + koff);
            A[1][ks][0] = *(const bf16x8*)(src + (size_t)a10 * CIN + ks * 32 + koff);
            A[1][ks][1] = *(const bf16x8*)(src + (size_t)a11 * CIN + ks * 32 + koff);
        }
        mi0c = midx[mb0 + 2];
        mi1c = midx[mb1 + 2];
    }

#pragma unroll
    for (int k = 0; k < KNBR; ++k) {
        // 1) issue A(k+2) into slot (k+2)%3 using midx prefetched last iter
        if (k + 2 < KNBR) {
#pragma unroll
            for (int ks = 0; ks < KS; ++ks) {
                A[(k + 2) % 3][ks][0] =
                    *(const bf16x8*)(src + (size_t)mi0c * CIN + ks * 32 + koff);
                A[(k + 2) % 3][ks][1] =
                    *(const bf16x8*)(src + (size_t)mi1c * CIN + ks * 32 + koff);
            }
        }
        // 2) refill midx prefetch for k+3
        if (k + 3 < KNBR) {
            mi0c = midx[mb0 + k + 3];
            mi1c = midx[mb1 + k + 3];
        }
        // 3) B(k) direct (contiguous 1KB wave-reads, L2-hot)
        bf16x8 B[KS][4];
#pragma unroll
        for (int ks = 0; ks < KS; ++ks)
#pragma unroll
            for (int c = 0; c < 4; ++c)
                B[ks][c] = *(const bf16x8*)(wtf + (size_t)k * (CIN * 64)
                                                + ((ks * 4 + c) * 64 + lane) * 8);
        // 4) MFMAs on slot k%3
#pragma unroll
        for (int ks = 0; ks < KS; ++ks)
#pragma unroll
            for (int c = 0; c < 4; ++c)
#pragma unroll
                for (int ai = 0; ai < 2; ++ai)
                    acc[c][ai] = __builtin_amdgcn_mfma_f32_16x16x32_bf16(
                        A[k % 3][ks][ai], B[ks][c], acc[c][ai], 0, 0, 0);
    }

    // ---- epilogue: D col=lr, row=kg*4+r (verified R3-R6); fused BN stats ----
    float s[4], q[4];
#pragma unroll
    for (int c = 0; c < 4; ++c) { s[c] = 0.f; q[c] = 0.f; }

#pragma unroll
    for (int c = 0; c < 4; ++c) {
#pragma unroll
        for (int ai = 0; ai < 2; ++ai) {
#pragma unroll
            for (int r = 0; r < 4; ++r) {
                const float v = acc[c][ai][r];
                s[c] += v;
                q[c] = fmaf(v, v, q[c]);
                const int row = pbase + wpt + ai * 16 + kg * 4 + r;
                if (row < NPTS) {
                    if (OUT_BF16)
                        ((unsigned short*)outp)[(size_t)row * NCH + c * 16 + lr] = f2bf(v);
                    else  // final output: never re-read -> bypass caches
                        __builtin_nontemporal_store(
                            v, &((float*)outp)[(size_t)row * NCH + c * 16 + lr]);
                }
            }
        }
    }
#pragma unroll
    for (int c = 0; c < 4; ++c) {
        atomicAdd(&sred[c * 16 + lr], s[c]);
        atomicAdd(&qred[c * 16 + lr], q[c]);
    }
    __syncthreads();
    if (t < 64) {
        atomicAdd(&sums[t], sred[t]);
        atomicAdd(&sums[64 + t], qred[t]);
    }
}

// sums -> folded scale/shift:  bn(x) = x*scale + shift
__global__ void finalize_kernel(const float* __restrict__ sums,
                                const float* __restrict__ gamma,
                                const float* __restrict__ beta,
                                float* __restrict__ ss)
{
    const int c = threadIdx.x;
    if (c < NCH) {
        const float inv = 1.0f / (float)NPTS;
        float mu  = sums[c] * inv;
        float var = sums[NCH + c] * inv - mu * mu;
        float rs  = 1.0f / sqrtf(var + EPSV);
        float scv = gamma[c] * rs;
        ss[c]       = scv;
        ss[NCH + c] = beta[c] - mu * scv;
    }
}

// In-place bf16 y = relu(x*sc+sh); h1 must STAY cached (conv2 gathers it).
__global__ __launch_bounds__(256)
void bnrelu_bf16_kernel(unsigned short* __restrict__ x, const float* __restrict__ ss)
{
    const int t = threadIdx.x;
    const int c0 = (t & 7) * 8;
    float sc[8], sh[8];
#pragma unroll
    for (int j = 0; j < 8; ++j) { sc[j] = ss[c0 + j]; sh[j] = ss[NCH + c0 + j]; }
    const long nchunk = (long)NPTS * NCH / 8;
    const long stride = (long)gridDim.x * 256;
    ushort8* x8 = (ushort8*)x;
    for (long i = (long)blockIdx.x * 256 + t; i < nchunk; i += stride) {
        ushort8 v = x8[i];
#pragma unroll
        for (int j = 0; j < 8; ++j) {
            float f = fmaxf(fmaf(bf2f(v[j]), sc[j], sh[j]), 0.0f);
            v[j] = f2bf(f);
        }
        x8[i] = v;
    }
}

// In-place fp32 y = relu(x*sc+sh) on the final output: fully nontemporal.
__global__ __launch_bounds__(256)
void bnrelu_f32_kernel(float* __restrict__ x, const float* __restrict__ ss, long n4)
{
    const int t = threadIdx.x;
    const int c0 = (t * 4) & 63;
    const float4 sc = *(const float4*)&ss[c0];
    const float4 sh = *(const float4*)&ss[NCH + c0];
    const long stride = (long)gridDim.x * 256;
    f32x4* x4 = (f32x4*)x;
    for (long i = (long)blockIdx.x * 256 + t; i < n4; i += stride) {
        f32x4 v = __builtin_nontemporal_load(&x4[i]);
        v.x = fmaxf(fmaf(v.x, sc.x, sh.x), 0.0f);
        v.y = fmaxf(fmaf(v.y, sc.y, sh.y), 0.0f);
        v.z = fmaxf(fmaf(v.z, sc.z, sh.z), 0.0f);
        v.w = fmaxf(fmaf(v.w, sc.w, sh.w), 0.0f);
        __builtin_nontemporal_store(v, &x4[i]);
    }
}

extern "C" void kernel_launch(void* const* d_in, const int* in_sizes, int n_in,
                              void* d_out, int out_size, void* d_ws, size_t ws_size,
                              hipStream_t stream)
{
    const float* feats  = (const float*)d_in[0];
    const float* W1     = (const float*)d_in[1];
    const float* W2     = (const float*)d_in[2];
    const float* gamma1 = (const float*)d_in[3];
    const float* beta1  = (const float*)d_in[4];
    const float* gamma2 = (const float*)d_in[5];
    const float* beta2  = (const float*)d_in[6];
    const int* nbr      = (const int*)d_in[7];
    const unsigned char* mask8 = (const unsigned char*)d_in[8];
    const int* mask32          = (const int*)d_in[8];
    float* out = (float*)d_out;

    // ---- workspace layout (tables have N+1 rows; row N = zero sentinel) ----
    char* w = (char*)d_ws;
    unsigned short* h1  = (unsigned short*)w;                     // [N+1][64] bf16
    unsigned short* fb  = (unsigned short*)(w + 128000512);       // [N+1][32] bf16
    unsigned short* wt1 = (unsigned short*)(w + 192001024);       // 110,592 B
    unsigned short* wt2 = (unsigned short*)(w + 192112128);       // 221,184 B
    float* stats        = (float*)(w + 192400000);                // 512 f32
    int*   mflag        = (int*)(w + 192500000);
    // stats: [0:128) sums1 | [128:256) ss1 | [256:384) sums2 | [384:512) ss2

    (void)hipMemsetAsync(stats, 0, 512 * sizeof(float), stream);
    detect_mask_kernel<<<1, 256, 0, stream>>>((const unsigned int*)d_in[8], mflag);

    cvt_feats_kernel<<<2048, 256, 0, stream>>>(feats, fb);
    zero_rows_kernel<<<1, 64, 0, stream>>>(fb, h1);
    transpose_w_frag_kernel<32><<<KNBR, 256, 0, stream>>>(W1, wt1);
    transpose_w_frag_kernel<64><<<KNBR, 256, 0, stream>>>(W2, wt2);

    const int conv_grid = (NPTS + 127) / 128;   // 7813
    const long n4 = (long)NPTS * NCH / 4;

    conv_mfma_kernel<32, true><<<conv_grid, 256, 0, stream>>>(
        fb, wt1, nbr, mask8, mask32, mflag, h1, stats);
    finalize_kernel<<<1, 64, 0, stream>>>(stats, gamma1, beta1, stats + 128);
    bnrelu_bf16_kernel<<<2048, 256, 0, stream>>>(h1, stats + 128);

    conv_mfma_kernel<64, false><<<conv_grid, 256, 0, stream>>>(
        h1, wt2, nbr, mask8, mask32, mflag, out, stats + 256);
    finalize_kernel<<<1, 64, 0, stream>>>(stats + 256, gamma2, beta2, stats + 384);
    bnrelu_f32_kernel<<<2048, 256, 0, stream>>>(out, stats + 384, n4);
}